// Round 1
// baseline (381.454 us; speedup 1.0000x reference)
//
#include <hip/hip_runtime.h>
#include <stdint.h>

// Problem constants
#define BTOT 32768
#define NIMG 16      // images per conv block
#define IS   692     // padded image stride in dwords (used: 3*14*16 = 672; 692/4=173 chunks, odd mod 8 -> bank spread)
#define CH   224     // channel stride in dwords (14 rows * 16)
#define KF   416     // padded feature dim (400 real)

__device__ __forceinline__ unsigned short f2bf(float x) {
    union { float f; unsigned int u; } v; v.f = x;
    unsigned int r = v.u + 0x7fffu + ((v.u >> 16) & 1u);  // RNE
    return (unsigned short)(r >> 16);
}

// ---------------- conv(5x5,3->16) + bias + relu + 2x2 maxpool -> bf16 features ----------------
// thread = (b_local, co); computes full 10x10 conv plane in 5 pool-row strips of 2 rows.
__global__ __launch_bounds__(256) void conv_pool_kernel(
    const float* __restrict__ fm, const float* __restrict__ cw,
    const float* __restrict__ cb, unsigned short* __restrict__ feat)
{
    __shared__ __align__(16) float s_img[NIMG * IS];
    __shared__ float s_w[16 * 76];

    const int tid = threadIdx.x;
    const int b0 = blockIdx.x * NIMG;

    // stage 16 images (16*588 floats) into LDS, padded rows of 16
    const float4* in4 = (const float4*)(fm);
    for (int idx = tid; idx < NIMG * 147; idx += 256) {
        float4 v = in4[(size_t)b0 * 147 + idx];
        int f = idx * 4;
        #pragma unroll
        for (int j = 0; j < 4; ++j) {
            int e = f + j;
            int img = e / 588;
            int r = e - img * 588;
            int ci = r / 196;
            int r2 = r - ci * 196;
            int row = r2 / 14;
            int col = r2 - row * 14;
            float val = (j == 0) ? v.x : (j == 1) ? v.y : (j == 2) ? v.z : v.w;
            s_img[img * IS + ci * CH + row * 16 + col] = val;
        }
    }
    // stage conv weights [16][75] padded to [16][76]
    for (int idx = tid; idx < 1200; idx += 256) {
        int co = idx / 75;
        int r = idx - co * 75;
        s_w[co * 76 + r] = cw[idx];
    }
    __syncthreads();

    const int b_local = tid & 15;
    const int co = tid >> 4;
    const int b = b0 + b_local;
    const float bias = cb[co];
    const float* ibase = &s_img[b_local * IS];
    const float* wbase = &s_w[co * 76];
    unsigned short* fout = feat + (size_t)b * KF + co * 25;

    for (int r = 0; r < 5; ++r) {           // pool row: conv rows 2r, 2r+1
        float acc0[10], acc1[10];
        #pragma unroll
        for (int i = 0; i < 10; ++i) { acc0[i] = 0.f; acc1[i] = 0.f; }
        for (int ci = 0; ci < 3; ++ci) {
            const float* ip = ibase + ci * CH + 2 * r * 16;
            const float* wp = wbase + ci * 25;
            float wc[5], wl[5];
            #pragma unroll
            for (int ir = 0; ir < 6; ++ir) {  // input rows 2r .. 2r+5
                float rv[16];
                const float4* rp = (const float4*)(ip + ir * 16);
                #pragma unroll
                for (int q = 0; q < 4; ++q) ((float4*)rv)[q] = rp[q];
                if (ir < 5) {
                    #pragma unroll
                    for (int kw = 0; kw < 5; ++kw) wc[kw] = wp[ir * 5 + kw];
                }
                if (ir >= 1) {                 // conv row 2r+1, kh = ir-1
                    #pragma unroll
                    for (int kw = 0; kw < 5; ++kw) {
                        #pragma unroll
                        for (int ow = 0; ow < 10; ++ow)
                            acc1[ow] += rv[ow + kw] * wl[kw];
                    }
                }
                if (ir < 5) {                  // conv row 2r, kh = ir
                    #pragma unroll
                    for (int kw = 0; kw < 5; ++kw) {
                        #pragma unroll
                        for (int ow = 0; ow < 10; ++ow)
                            acc0[ow] += rv[ow + kw] * wc[kw];
                    }
                }
                #pragma unroll
                for (int kw = 0; kw < 5; ++kw) wl[kw] = wc[kw];
            }
        }
        #pragma unroll
        for (int pw = 0; pw < 5; ++pw) {
            float m = fmaxf(fmaxf(acc0[2 * pw], acc0[2 * pw + 1]),
                            fmaxf(acc1[2 * pw], acc1[2 * pw + 1]));
            m += bias;
            m = m > 0.f ? m : 0.f;
            fout[r * 5 + pw] = f2bf(m);
        }
    }
    if (co == 0) {   // zero-pad features[b][400..415]
        uint4 z = make_uint4(0u, 0u, 0u, 0u);
        *(uint4*)(feat + (size_t)b * KF + 400) = z;
        *(uint4*)(feat + (size_t)b * KF + 408) = z;
    }
}

// ---------------- lin_w [1000][400] fp32 -> Wb [1024][416] bf16 (zero padded) ----------------
__global__ __launch_bounds__(256) void prep_w_kernel(const float* __restrict__ lw,
                                                     unsigned short* __restrict__ Wb)
{
    int c = blockIdx.x * 256 + threadIdx.x;   // one 8-element chunk
    if (c >= 1024 * 52) return;
    int n = c / 52;
    int kc = (c - n * 52) * 8;
    unsigned short v[8];
    #pragma unroll
    for (int j = 0; j < 8; ++j) {
        int k = kc + j;
        float x = (n < 1000 && k < 400) ? lw[n * 400 + k] : 0.f;
        v[j] = f2bf(x);
    }
    *(uint4*)(Wb + (size_t)n * KF + kc) = *(uint4*)v;
}

// ---------------- GEMM: out[32768][1000] = F[32768][416] @ Wb[1024][416]^T + lin_b ----------------
typedef __attribute__((ext_vector_type(8))) short short8;
typedef __attribute__((ext_vector_type(4))) float floatx4;

__global__ __launch_bounds__(256) void gemm_kernel(
    const unsigned short* __restrict__ F, const unsigned short* __restrict__ Wb,
    const float* __restrict__ lb, float* __restrict__ out)
{
    __shared__ __align__(16) unsigned short At[128 * 32];
    __shared__ __align__(16) unsigned short Bt[128 * 32];

    const int tid = threadIdx.x;
    const int bm = blockIdx.x >> 3;
    const int bn = blockIdx.x & 7;
    const int m0 = bm * 128;
    const int n0 = bn * 128;

    const int w = tid >> 6;
    const int lane = tid & 63;
    const int wm = w & 1, wn = w >> 1;     // 2x2 wave grid, each wave 64x64
    const int lq = lane >> 4, ln = lane & 15;

    floatx4 zero = {0.f, 0.f, 0.f, 0.f};
    floatx4 acc[4][4];
    #pragma unroll
    for (int i = 0; i < 4; ++i) {
        #pragma unroll
        for (int j = 0; j < 4; ++j) acc[i][j] = zero;
    }

    const int r0 = tid >> 2;   // staging row (t=0)
    const int kc = tid & 3;    // staging k-chunk (8 halves)

    for (int kb = 0; kb < KF; kb += 32) {
        #pragma unroll
        for (int t = 0; t < 2; ++t) {
            int row = r0 + t * 64;
            const uint4* sa = (const uint4*)(F + (size_t)(m0 + row) * KF + kb + kc * 8);
            *(uint4*)&At[(row * 4 + kc) * 8] = *sa;
            const uint4* sb = (const uint4*)(Wb + (size_t)(n0 + row) * KF + kb + kc * 8);
            *(uint4*)&Bt[(row * 4 + kc) * 8] = *sb;
        }
        __syncthreads();
        short8 af[4], bf[4];
        #pragma unroll
        for (int i = 0; i < 4; ++i)
            af[i] = *(const short8*)&At[(wm * 64 + i * 16 + ln) * 32 + lq * 8];
        #pragma unroll
        for (int j = 0; j < 4; ++j)
            bf[j] = *(const short8*)&Bt[(wn * 64 + j * 16 + ln) * 32 + lq * 8];
        #pragma unroll
        for (int i = 0; i < 4; ++i) {
            #pragma unroll
            for (int j = 0; j < 4; ++j)
                acc[i][j] = __builtin_amdgcn_mfma_f32_16x16x32_bf16(af[i], bf[j], acc[i][j], 0, 0, 0);
        }
        __syncthreads();
    }

    #pragma unroll
    for (int j = 0; j < 4; ++j) {
        int n = n0 + wn * 64 + j * 16 + ln;
        if (n >= 1000) continue;           // padded N region
        float bias = lb[n];
        #pragma unroll
        for (int i = 0; i < 4; ++i) {
            int mb = m0 + wm * 64 + i * 16 + lq * 4;   // C/D: col=lane&15, row=quad*4+reg (m89/m91)
            #pragma unroll
            for (int rr = 0; rr < 4; ++rr)
                out[(size_t)(mb + rr) * 1000 + n] = acc[i][j][rr] + bias;
        }
    }
}

extern "C" void kernel_launch(void* const* d_in, const int* in_sizes, int n_in,
                              void* d_out, int out_size, void* d_ws, size_t ws_size,
                              hipStream_t stream)
{
    const float* fm = (const float*)d_in[0];   // (32768,3,14,14)
    const float* cw = (const float*)d_in[1];   // (16,3,5,5)
    const float* cb = (const float*)d_in[2];   // (16,)
    const float* lw = (const float*)d_in[3];   // (1000,400)
    const float* lb = (const float*)d_in[4];   // (1000,)
    float* out = (float*)d_out;                // (32768,1000) fp32

    unsigned short* feat = (unsigned short*)d_ws;                        // [32768][416] bf16
    unsigned short* Wb   = (unsigned short*)d_ws + (size_t)BTOT * KF;    // [1024][416] bf16

    prep_w_kernel<<<208, 256, 0, stream>>>(lw, Wb);
    conv_pool_kernel<<<BTOT / NIMG, 256, 0, stream>>>(fm, cw, cb, feat);
    gemm_kernel<<<2048, 256, 0, stream>>>(feat, Wb, lb, out);
}

// Round 3
// 339.339 us; speedup vs baseline: 1.1241x; 1.1241x over previous
//
#include <hip/hip_runtime.h>
#include <stdint.h>

#define BTOT 32768
#define NIMG 16      // images per conv block
#define KF   416     // padded feature dim (400 real)

typedef __attribute__((ext_vector_type(2))) _Float16 half2r;
typedef __attribute__((ext_vector_type(8))) short short8;
typedef __attribute__((ext_vector_type(4))) float floatx4;

static __device__ __forceinline__ half2r u2h(unsigned int u) {
    return __builtin_bit_cast(half2r, u);
}
static __device__ __forceinline__ unsigned int h2u(half2r h) {
    return __builtin_bit_cast(unsigned int, h);
}
static __device__ __forceinline__ half2r cvt2h(float a, float b) {
    return __builtin_bit_cast(half2r, __builtin_amdgcn_cvt_pkrtz(a, b));
}
__device__ __forceinline__ unsigned short f2bf(float x) {
    union { float f; unsigned int u; } v; v.f = x;
    unsigned int r = v.u + 0x7fffu + ((v.u >> 16) & 1u);  // RNE
    return (unsigned short)(r >> 16);
}

// ---------------- conv(5x5,3->16) + bias + relu + 2x2 maxpool -> bf16 features ----------------
// f16 packed math: thread = (b_local, co); acc half2 = pool-pair (out[2p], out[2p+1]).
// LDS: images f16 flat (588 halves = 294 dwords per image, stride 294 % 32 = 6 -> conflict-free),
//      weights as duplicated f16 pairs [16][76].
__global__ __launch_bounds__(256) void conv_pool_kernel(
    const float* __restrict__ fm, const float* __restrict__ cw,
    const float* __restrict__ cb, unsigned short* __restrict__ feat)
{
    __shared__ __align__(16) unsigned int s_img[NIMG * 294];
    __shared__ unsigned int s_w2[16 * 76];

    const int tid = threadIdx.x;
    const int b0 = blockIdx.x * NIMG;

    // stage images fp32 -> f16, layout-preserving flat copy (no index math)
    const float4* in4 = (const float4*)fm;
    for (int idx = tid; idx < NIMG * 147; idx += 256) {
        float4 v = in4[(size_t)b0 * 147 + idx];
        half2r lo = cvt2h(v.x, v.y);
        half2r hi = cvt2h(v.z, v.w);
        *(uint2*)&s_img[idx * 2] = make_uint2(h2u(lo), h2u(hi));
    }
    // stage conv weights as duplicated f16 pairs
    for (int idx = tid; idx < 1200; idx += 256) {
        int co = idx / 75;
        int r = idx - co * 75;
        float w = cw[idx];
        s_w2[co * 76 + r] = h2u(cvt2h(w, w));
    }
    __syncthreads();

    const int b_local = tid & 15;
    const int co = tid >> 4;
    const float bias = cb[co];
    const unsigned int* ibase = s_img + b_local * 294;  // dword units
    const unsigned int* wbase = s_w2 + co * 76;
    unsigned short* fout = feat + (size_t)(b0 + b_local) * KF + co * 25;

    for (int r = 0; r < 5; ++r) {           // pool-row strip: conv rows 2r, 2r+1
        half2r acc0[5], acc1[5];
        #pragma unroll
        for (int p = 0; p < 5; ++p) { acc0[p] = u2h(0u); acc1[p] = u2h(0u); }

        #pragma unroll
        for (int ci = 0; ci < 3; ++ci) {
            const unsigned int* ip = ibase + ci * 98 + r * 14;  // rows of 7 dwords (14 halves)
            unsigned int wr[25];
            #pragma unroll
            for (int k = 0; k < 25; ++k) wr[k] = wbase[ci * 25 + k];

            #pragma unroll
            for (int ir = 0; ir < 6; ++ir) {   // input rows 2r..2r+5
                unsigned int v[7];
                #pragma unroll
                for (int q = 0; q < 7; ++q) v[q] = ip[ir * 7 + q];
                unsigned int s[6];              // odd-offset pairs
                #pragma unroll
                for (int q = 0; q < 6; ++q) s[q] = (v[q] >> 16) | (v[q + 1] << 16);

                if (ir < 5) {                   // conv row 2r, kh = ir
                    #pragma unroll
                    for (int p = 0; p < 5; ++p) {
                        acc0[p] += u2h(v[p])     * u2h(wr[ir * 5 + 0]);
                        acc0[p] += u2h(s[p])     * u2h(wr[ir * 5 + 1]);
                        acc0[p] += u2h(v[p + 1]) * u2h(wr[ir * 5 + 2]);
                        acc0[p] += u2h(s[p + 1]) * u2h(wr[ir * 5 + 3]);
                        acc0[p] += u2h(v[p + 2]) * u2h(wr[ir * 5 + 4]);
                    }
                }
                if (ir >= 1) {                  // conv row 2r+1, kh = ir-1
                    const int kh = ir - 1;
                    #pragma unroll
                    for (int p = 0; p < 5; ++p) {
                        acc1[p] += u2h(v[p])     * u2h(wr[kh * 5 + 0]);
                        acc1[p] += u2h(s[p])     * u2h(wr[kh * 5 + 1]);
                        acc1[p] += u2h(v[p + 1]) * u2h(wr[kh * 5 + 2]);
                        acc1[p] += u2h(s[p + 1]) * u2h(wr[kh * 5 + 3]);
                        acc1[p] += u2h(v[p + 2]) * u2h(wr[kh * 5 + 4]);
                    }
                }
            }
        }
        // 2x2 pool + bias + relu + bf16 store
        #pragma unroll
        for (int p = 0; p < 5; ++p) {
            float a = (float)acc0[p].x, b = (float)acc0[p].y;
            float c = (float)acc1[p].x, d = (float)acc1[p].y;
            float m = fmaxf(fmaxf(a, b), fmaxf(c, d)) + bias;
            m = fmaxf(m, 0.f);
            fout[r * 5 + p] = f2bf(m);
        }
    }
    if (co == 0) {   // zero-pad features[b][400..415]
        uint4 z = make_uint4(0u, 0u, 0u, 0u);
        *(uint4*)(feat + (size_t)(b0 + b_local) * KF + 400) = z;
        *(uint4*)(feat + (size_t)(b0 + b_local) * KF + 408) = z;
    }
}

// ---------------- lin_w [1000][400] fp32 -> Wb [1024][416] bf16 (zero padded) ----------------
__global__ __launch_bounds__(256) void prep_w_kernel(const float* __restrict__ lw,
                                                     unsigned short* __restrict__ Wb)
{
    int c = blockIdx.x * 256 + threadIdx.x;   // one 8-element chunk
    if (c >= 1024 * 52) return;
    int n = c / 52;
    int kc = (c - n * 52) * 8;
    unsigned short v[8];
    #pragma unroll
    for (int j = 0; j < 8; ++j) {
        int k = kc + j;
        float x = (n < 1000 && k < 400) ? lw[n * 400 + k] : 0.f;
        v[j] = f2bf(x);
    }
    *(uint4*)(Wb + (size_t)n * KF + kc) = *(uint4*)v;
}

// ---------------- GEMM: out[32768][1000] = F[32768][416] @ Wb[1024][416]^T + lin_b ----------------
// m97 pattern: global_load_lds width=16 staging (dest = wave-uniform base + lane*16).
__global__ __launch_bounds__(256) void gemm_kernel(
    const unsigned short* __restrict__ F, const unsigned short* __restrict__ Wb,
    const float* __restrict__ lb, float* __restrict__ out)
{
    __shared__ __align__(16) unsigned short At[128 * 32];
    __shared__ __align__(16) unsigned short Bt[128 * 32];

    const int tid = threadIdx.x;
    const int bm = blockIdx.x >> 3;
    const int bn = blockIdx.x & 7;
    const int m0 = bm * 128;
    const int n0 = bn * 128;

    const int w = tid >> 6;
    const int lane = tid & 63;
    const int wm = w & 1, wn = w >> 1;     // 2x2 wave grid, each wave 64x64
    const int lq = lane >> 4, ln = lane & 15;

    floatx4 zero = {0.f, 0.f, 0.f, 0.f};
    floatx4 acc[4][4];
    #pragma unroll
    for (int i = 0; i < 4; ++i)
        #pragma unroll
        for (int j = 0; j < 4; ++j) acc[i][j] = zero;

    // staging: wave w covers rows [w*16, w*16+16) (+64 for t=1); lane L -> row w*16+(L>>2), chunk L&3
    const int srow = w * 16 + (lane >> 2);
    const int skc = (lane & 3) * 8;
    const unsigned short* gA = F + (size_t)(m0 + srow) * KF + skc;
    const unsigned short* gB = Wb + (size_t)(n0 + srow) * KF + skc;

    for (int kb = 0; kb < KF; kb += 32) {
        #pragma unroll
        for (int t = 0; t < 2; ++t) {
            __builtin_amdgcn_global_load_lds(
                (const __attribute__((address_space(1))) void*)(gA + (size_t)(t * 64) * KF + kb),
                (__attribute__((address_space(3))) void*)&At[(w * 16 + t * 64) * 32],
                16, 0, 0);
            __builtin_amdgcn_global_load_lds(
                (const __attribute__((address_space(1))) void*)(gB + (size_t)(t * 64) * KF + kb),
                (__attribute__((address_space(3))) void*)&Bt[(w * 16 + t * 64) * 32],
                16, 0, 0);
        }
        __syncthreads();
        short8 af[4], bf[4];
        #pragma unroll
        for (int i = 0; i < 4; ++i)
            af[i] = *(const short8*)&At[(wm * 64 + i * 16 + ln) * 32 + lq * 8];
        #pragma unroll
        for (int j = 0; j < 4; ++j)
            bf[j] = *(const short8*)&Bt[(wn * 64 + j * 16 + ln) * 32 + lq * 8];
        #pragma unroll
        for (int i = 0; i < 4; ++i)
            #pragma unroll
            for (int j = 0; j < 4; ++j)
                acc[i][j] = __builtin_amdgcn_mfma_f32_16x16x32_bf16(af[i], bf[j], acc[i][j], 0, 0, 0);
        __syncthreads();
    }

    #pragma unroll
    for (int j = 0; j < 4; ++j) {
        int n = n0 + wn * 64 + j * 16 + ln;
        if (n >= 1000) continue;           // padded N region
        float bias = lb[n];
        #pragma unroll
        for (int i = 0; i < 4; ++i) {
            int mb = m0 + wm * 64 + i * 16 + lq * 4;   // C/D: col=lane&15, row=quad*4+reg (m89/m91)
            #pragma unroll
            for (int rr = 0; rr < 4; ++rr)
                out[(size_t)(mb + rr) * 1000 + n] = acc[i][j][rr] + bias;
        }
    }
}

extern "C" void kernel_launch(void* const* d_in, const int* in_sizes, int n_in,
                              void* d_out, int out_size, void* d_ws, size_t ws_size,
                              hipStream_t stream)
{
    const float* fm = (const float*)d_in[0];   // (32768,3,14,14)
    const float* cw = (const float*)d_in[1];   // (16,3,5,5)
    const float* cb = (const float*)d_in[2];   // (16,)
    const float* lw = (const float*)d_in[3];   // (1000,400)
    const float* lb = (const float*)d_in[4];   // (1000,)
    float* out = (float*)d_out;                // (32768,1000) fp32

    unsigned short* feat = (unsigned short*)d_ws;                        // [32768][416] bf16
    unsigned short* Wb   = (unsigned short*)d_ws + (size_t)BTOT * KF;    // [1024][416] bf16

    prep_w_kernel<<<208, 256, 0, stream>>>(lw, Wb);
    conv_pool_kernel<<<BTOT / NIMG, 256, 0, stream>>>(fm, cw, cb, feat);
    gemm_kernel<<<2048, 256, 0, stream>>>(feat, Wb, lb, out);
}